// Round 3
// baseline (231.277 us; speedup 1.0000x reference)
//
#include <hip/hip_runtime.h>
#include <hip/hip_bf16.h>

// Problem constants (reference: H=W=64, C=2048, IMG=224)
#define HW    4096          // H*W rows
#define CDIM  2048          // channels (K)
#define IMG   224
#define NTK   128           // K tiles of 16: CDIM/16
#define NTM   128           // row tiles of 32: HW/32

typedef short short8  __attribute__((ext_vector_type(8)));   // 8 bf16, 4 VGPRs
typedef float f32x4   __attribute__((ext_vector_type(4)));
typedef float f32x16  __attribute__((ext_vector_type(16)));

__device__ __forceinline__ short f32_to_bf16s(float f) {
    return __builtin_bit_cast(short, __float2bfloat16(f));
}
__device__ __forceinline__ f32x16 z16() {
    f32x16 z;
#pragma unroll
    for (int i = 0; i < 16; ++i) z[i] = 0.f;
    return z;
}

// ---------------------------------------------------------------------------
// Kernel 1: convert fp32 -> bf16 packed in MFMA-fragment order + column sums.
// Packed layout: tile (tm in [0,128), tk in [0,128)) holds rows tm*32..+31,
// k = tk*16..+15. Within tile: lane l holds row tm*32+(l&31),
// k = tk*16+(l>>5)*8 + j (j=0..7); short-offset = (tile*64 + l)*8.
// grid (32 tk-groups, 128 tm, 2 mats), block 256 (= 4 tk x 64 lanes).
__global__ __launch_bounds__(256) void convert_pack_colsum(
    const float* __restrict__ feat,
    short* __restrict__ Ap, short* __restrict__ Bp,
    float* __restrict__ s0, float* __restrict__ s1) {
    const int tid = threadIdx.x;
    const int l   = tid & 63;
    const int tk  = blockIdx.x * 4 + (tid >> 6);
    const int tm  = blockIdx.y;
    const int mat = blockIdx.z;
    const int row = tm * 32 + (l & 31);
    const int kb  = tk * 16 + (l >> 5) * 8;

    const float* src = feat + (size_t)mat * HW * CDIM + (size_t)row * CDIM + kb;
    float4 f0 = *(const float4*)src;
    float4 f1 = *(const float4*)(src + 4);

    short8 o;
    o[0] = f32_to_bf16s(f0.x); o[1] = f32_to_bf16s(f0.y);
    o[2] = f32_to_bf16s(f0.z); o[3] = f32_to_bf16s(f0.w);
    o[4] = f32_to_bf16s(f1.x); o[5] = f32_to_bf16s(f1.y);
    o[6] = f32_to_bf16s(f1.z); o[7] = f32_to_bf16s(f1.w);
    short* dst = (mat ? Bp : Ap) + ((size_t)(tm * NTK + tk) * 64 + l) * 8;
    *(short8*)dst = o;

    // column partial sums: reduce over the 32 row-lanes (lane bits 0..4).
    float p[8] = {f0.x, f0.y, f0.z, f0.w, f1.x, f1.y, f1.z, f1.w};
#pragma unroll
    for (int off = 1; off < 32; off <<= 1)
#pragma unroll
        for (int j = 0; j < 8; ++j) p[j] += __shfl_xor(p[j], off);
    if ((l & 31) == 0) {
        float* s = mat ? s1 : s0;
#pragma unroll
        for (int j = 0; j < 8; ++j) atomicAdd(&s[kb + j], p[j]);
    }
}

// ---------------------------------------------------------------------------
// Kernel 2: LDS-free GEMM-max. C = A * B^T over packed bf16 fragments; only
// the per-block max is kept. Block = 128x128 tile, 4 waves in 2x2; each wave
// computes 64x64 as 2x2 of 32x32x16 MFMAs, fragments loaded straight from
// global (perfectly coalesced 1KB per load, L1/L2-served). No barriers, no
// LDS staging -> no vmcnt(0) drain; compiler pipelines loads across MFMAs.
// Correctness note: any lane->(m,k) mis-mapping is applied identically to
// both operands (k-permutations cancel; m/n permutations only permute tile
// entries) -> max is invariant.
__global__ __launch_bounds__(256, 4) void gemm_max_kernel(
    const short* __restrict__ Ap, const short* __restrict__ Bp,
    float* __restrict__ blockmax) {
    const int tid  = threadIdx.x;
    const int lane = tid & 63;
    const int wave = tid >> 6;
    const int wm = wave >> 1, wn = wave & 1;
    const int bm = blockIdx.y, bn = blockIdx.x;

    const int tmA = bm * 4 + wm * 2;          // A tiles tmA, tmA+1
    const int tnB = bn * 4 + wn * 2;          // B tiles tnB, tnB+1
    const short* a0p = Ap + ((size_t)tmA * NTK * 64 + lane) * 8;
    const short* a1p = a0p + (size_t)NTK * 64 * 8;
    const short* b0p = Bp + ((size_t)tnB * NTK * 64 + lane) * 8;
    const short* b1p = b0p + (size_t)NTK * 64 * 8;
    // per-tk stride = 64 lanes * 8 shorts = 512 shorts

    f32x16 acc00 = z16(), acc01 = z16(), acc10 = z16(), acc11 = z16();

    short8 ca0 = *(const short8*)a0p;
    short8 ca1 = *(const short8*)a1p;
    short8 cb0 = *(const short8*)b0p;
    short8 cb1 = *(const short8*)b1p;

#pragma unroll 2
    for (int tk = 0; tk < NTK - 1; ++tk) {
        const short8 na0 = *(const short8*)(a0p + (size_t)(tk + 1) * 512);
        const short8 na1 = *(const short8*)(a1p + (size_t)(tk + 1) * 512);
        const short8 nb0 = *(const short8*)(b0p + (size_t)(tk + 1) * 512);
        const short8 nb1 = *(const short8*)(b1p + (size_t)(tk + 1) * 512);
        acc00 = __builtin_amdgcn_mfma_f32_32x32x16_bf16(ca0, cb0, acc00, 0, 0, 0);
        acc01 = __builtin_amdgcn_mfma_f32_32x32x16_bf16(ca0, cb1, acc01, 0, 0, 0);
        acc10 = __builtin_amdgcn_mfma_f32_32x32x16_bf16(ca1, cb0, acc10, 0, 0, 0);
        acc11 = __builtin_amdgcn_mfma_f32_32x32x16_bf16(ca1, cb1, acc11, 0, 0, 0);
        ca0 = na0; ca1 = na1; cb0 = nb0; cb1 = nb1;
    }
    acc00 = __builtin_amdgcn_mfma_f32_32x32x16_bf16(ca0, cb0, acc00, 0, 0, 0);
    acc01 = __builtin_amdgcn_mfma_f32_32x32x16_bf16(ca0, cb1, acc01, 0, 0, 0);
    acc10 = __builtin_amdgcn_mfma_f32_32x32x16_bf16(ca1, cb0, acc10, 0, 0, 0);
    acc11 = __builtin_amdgcn_mfma_f32_32x32x16_bf16(ca1, cb1, acc11, 0, 0, 0);

    // per-lane max over all 64 values (max is layout-invariant)
    float m = -3.4e38f;
#pragma unroll
    for (int i = 0; i < 16; ++i) {
        m = fmaxf(m, acc00[i]); m = fmaxf(m, acc01[i]);
        m = fmaxf(m, acc10[i]); m = fmaxf(m, acc11[i]);
    }
#pragma unroll
    for (int off = 32; off; off >>= 1)
        m = fmaxf(m, __shfl_down(m, off));

    __shared__ float wred[4];
    if (lane == 0) wred[wave] = m;
    __syncthreads();
    if (tid == 0)
        blockmax[blockIdx.y * gridDim.x + blockIdx.x] =
            fmaxf(fmaxf(wred[0], wred[1]), fmaxf(wred[2], wred[3]));
}

// ---------------------------------------------------------------------------
// Kernel 3: UNNORMALIZED saliency matvecs from fp32 features (float4 loads).
// sal[0..4095] = (x0 row g) . s1 ; sal[4096..8191] = (x1 row g-HW) . s0
// one wave per row; grid 2048 x 256 (4 rows/block).
__global__ __launch_bounds__(256) void saliency_kernel(
    const float* __restrict__ feat, const float* __restrict__ s0,
    const float* __restrict__ s1, float* __restrict__ sal) {
    const int tid = threadIdx.x, lane = tid & 63, wave = tid >> 6;
    const int g = blockIdx.x * 4 + wave;          // 0..8191
    const float* x;
    const float* s;
    if (g < HW) { x = feat + (size_t)g * CDIM;                          s = s1; }
    else        { x = feat + (size_t)HW * CDIM + (size_t)(g - HW) * CDIM; s = s0; }
    float acc = 0.f;
#pragma unroll
    for (int it = 0; it < 8; ++it) {
        const int c0 = it * 256 + lane * 4;
        float4 v = *(const float4*)&x[c0];
        float4 w = *(const float4*)&s[c0];
        acc += v.x * w.x + v.y * w.y + v.z * w.z + v.w * w.w;
    }
#pragma unroll
    for (int off = 32; off; off >>= 1) acc += __shfl_down(acc, off);
    if (lane == 0) sal[g] = acc;
}

// ---------------------------------------------------------------------------
// Kernel 4: fused max-reduce + normalize + half-pixel bilinear 64->224.
__global__ __launch_bounds__(256) void resize_kernel(
    const float* __restrict__ sal, const float* __restrict__ bmax,
    float* __restrict__ out) {
    __shared__ float w[4];
    __shared__ float rM;
    const int tid = threadIdx.x;
    float m = -3.4e38f;
    for (int i = tid; i < 1024; i += 256) m = fmaxf(m, bmax[i]);
#pragma unroll
    for (int off = 32; off; off >>= 1) m = fmaxf(m, __shfl_down(m, off));
    if ((tid & 63) == 0) w[tid >> 6] = m;
    __syncthreads();
    if (tid == 0)
        rM = 1.0f / fmaxf(fmaxf(w[0], w[1]), fmaxf(w[2], w[3]));
    __syncthreads();

    const int idx = blockIdx.x * 256 + tid;
    if (idx >= 2 * IMG * IMG) return;
    const int ch = idx / (IMG * IMG);
    const int rem = idx % (IMG * IMG);
    const int oy = rem / IMG, ox = rem % IMG;
    const float scale = 64.0f / (float)IMG;
    const float sy = ((float)oy + 0.5f) * scale - 0.5f;
    const float sx = ((float)ox + 0.5f) * scale - 0.5f;
    const float fy0 = floorf(sy), fx0 = floorf(sx);
    const float wy = sy - fy0, wx = sx - fx0;
    int y0 = (int)fy0, x0 = (int)fx0;
    int y1 = min(max(y0 + 1, 0), 63), x1 = min(max(x0 + 1, 0), 63);
    y0 = min(max(y0, 0), 63); x0 = min(max(x0, 0), 63);
    const float* p = sal + ch * HW;
    const float v00 = p[y0 * 64 + x0], v01 = p[y0 * 64 + x1];
    const float v10 = p[y1 * 64 + x0], v11 = p[y1 * 64 + x1];
    out[idx] = ((1.f - wy) * ((1.f - wx) * v00 + wx * v01) +
                wy * ((1.f - wx) * v10 + wx * v11)) * rM;
}

// ---------------------------------------------------------------------------
extern "C" void kernel_launch(void* const* d_in, const int* in_sizes, int n_in,
                              void* d_out, int out_size, void* d_ws, size_t ws_size,
                              hipStream_t stream) {
    const float* feat = (const float*)d_in[0];   // [2,64,64,2048] fp32
    float* out = (float*)d_out;                  // [2,224,224] fp32

    // workspace layout
    char* ws = (char*)d_ws;
    short* Ap = (short*)ws;                                         // 16 MB packed
    short* Bp = (short*)(ws + (size_t)16 * 1024 * 1024);            // 16 MB packed
    float* s0   = (float*)(ws + (size_t)32 * 1024 * 1024);          // 2048
    float* s1   = s0 + CDIM;                                        // 2048
    float* bmax = s1 + CDIM;                                        // 1024
    float* sal  = bmax + 1024;                                      // 8192

    // zero the column-sum accumulators (ws is poisoned 0xAA each launch)
    hipMemsetAsync(s0, 0, 2 * CDIM * sizeof(float), stream);

    convert_pack_colsum<<<dim3(32, 128, 2), 256, 0, stream>>>(feat, Ap, Bp, s0, s1);
    gemm_max_kernel<<<dim3(32, 32), 256, 0, stream>>>(Ap, Bp, bmax);
    saliency_kernel<<<2048, 256, 0, stream>>>(feat, s0, s1, sal);
    const int nout = 2 * IMG * IMG;
    resize_kernel<<<(nout + 255) / 256, 256, 0, stream>>>(sal, bmax, out);
}

// Round 4
// 212.689 us; speedup vs baseline: 1.0874x; 1.0874x over previous
//
#include <hip/hip_runtime.h>
#include <hip/hip_bf16.h>

// Problem constants (reference: H=W=64, C=2048, IMG=224)
#define HW    4096          // H*W rows
#define CDIM  2048          // channels (K)
#define IMG   224
#define NTK   128           // K tiles of 16: CDIM/16
#define NTM   128           // row tiles of 32: HW/32
#define LPAD  520           // LDS row stride in shorts (+8 pad: stride 260 dwords)

typedef short short4v __attribute__((ext_vector_type(4)));
typedef short short8  __attribute__((ext_vector_type(8)));   // 8 bf16, 4 VGPRs
typedef float f32x16  __attribute__((ext_vector_type(16)));

__device__ __forceinline__ short f32_to_bf16s(float f) {
    return __builtin_bit_cast(short, __float2bfloat16(f));
}
__device__ __forceinline__ f32x16 z16() {
    f32x16 z;
#pragma unroll
    for (int i = 0; i < 16; ++i) z[i] = 0.f;
    return z;
}

// ---------------------------------------------------------------------------
// Kernel 1: convert fp32 -> bf16 packed in MFMA-fragment order, via LDS
// transpose so BOTH the global read and the packed write are coalesced.
// Packed tile (tm,tk): lane l holds row tm*32+(l&31), k = tk*16+(l>>5)*8+j.
// Block covers 32 rows x 512 k. grid (4, 128, 2), block 256.
__global__ __launch_bounds__(256) void convert_pack(
    const float* __restrict__ feat,
    short* __restrict__ Ap, short* __restrict__ Bp) {
    __shared__ short lds[32 * LPAD];
    const int tid = threadIdx.x;
    const int mat = blockIdx.z;
    const int tm  = blockIdx.y;
    const int kb0 = blockIdx.x * 512;
    const float* src = feat + (size_t)mat * HW * CDIM + (size_t)(tm * 32) * CDIM + kb0;

    // phase 1: coalesced read, 2 rows per iteration (128 threads/row)
#pragma unroll
    for (int j = 0; j < 16; ++j) {
        const int r = j * 2 + (tid >> 7);
        const int c = (tid & 127) * 4;
        float4 v = *(const float4*)&src[(size_t)r * CDIM + c];
        short4v o;
        o[0] = f32_to_bf16s(v.x); o[1] = f32_to_bf16s(v.y);
        o[2] = f32_to_bf16s(v.z); o[3] = f32_to_bf16s(v.w);
        *(short4v*)&lds[r * LPAD + c] = o;
    }
    __syncthreads();

    // phase 2: emit packed tiles; ds_read_b128 stride 260 dwords covers all
    // 32 banks across lanes 0..7 (conflict-free); store 1KB/wave contiguous.
    const int l = tid & 63, w = tid >> 6;
    short* dstbase = mat ? Bp : Ap;
#pragma unroll
    for (int i = 0; i < 8; ++i) {
        const int tkl = w * 8 + i;                 // local tile 0..31
        short8 v = *(const short8*)&lds[(l & 31) * LPAD + tkl * 16 + (l >> 5) * 8];
        const int tkg = blockIdx.x * 32 + tkl;
        *(short8*)&dstbase[((size_t)(tm * NTK + tkg) * 64 + l) * 8] = v;
    }
}

// ---------------------------------------------------------------------------
// Kernel 2: fused LDS-free GEMM producing (a) per-block max of C, (b) row
// sums of C (= decom_1, saliency on query), (c) col sums (= decom_2), all
// UNNORMALIZED. Block = 128x128 tile, 4 waves in 2x2, each wave 64x64 via
// 2x2 of 32x32x16 MFMAs. Depth-4 prefetch ring, fragments straight from
// global (1KB coalesced, L1/L2-served), no barriers in the K-loop.
// C/D layout (measured, m74/m101): col(n)=lane&31,
// row(m)=(reg&3)+8*(reg>>2)+4*(lane>>5).
__global__ __launch_bounds__(256, 3) void gemm_fused_kernel(
    const short* __restrict__ Ap, const short* __restrict__ Bp,
    float* __restrict__ sal1, float* __restrict__ sal2,
    float* __restrict__ blockmax) {
    const int tid  = threadIdx.x;
    const int lane = tid & 63;
    const int wave = tid >> 6;
    const int wm = wave >> 1, wn = wave & 1;
    const int bm = blockIdx.y, bn = blockIdx.x;

    const int tmA = bm * 4 + wm * 2;          // A tiles tmA, tmA+1
    const int tnB = bn * 4 + wn * 2;          // B tiles tnB, tnB+1
    const short* a0p = Ap + ((size_t)tmA * NTK * 64 + lane) * 8;
    const short* a1p = a0p + (size_t)NTK * 64 * 8;
    const short* b0p = Bp + ((size_t)tnB * NTK * 64 + lane) * 8;
    const short* b1p = b0p + (size_t)NTK * 64 * 8;
    // per-tk stride = 512 shorts (1KB)

    f32x16 acc00 = z16(), acc01 = z16(), acc10 = z16(), acc11 = z16();

    // depth-4 prefetch ring (fully unrolled -> static register indices)
    short8 ra0[4], ra1[4], rb0[4], rb1[4];
#pragma unroll
    for (int p = 0; p < 4; ++p) {
        ra0[p] = *(const short8*)(a0p + (size_t)p * 512);
        ra1[p] = *(const short8*)(a1p + (size_t)p * 512);
        rb0[p] = *(const short8*)(b0p + (size_t)p * 512);
        rb1[p] = *(const short8*)(b1p + (size_t)p * 512);
    }
#pragma unroll
    for (int tk = 0; tk < NTK; ++tk) {
        const int s = tk & 3;
        if (tk + 4 < NTK) {
            const size_t o = (size_t)(tk + 4) * 512;
            ra0[s] = ra0[s]; // keep slot live ordering explicit
        }
        // issue next loads BEFORE consuming current slot's data
        short8 na0, na1, nb0, nb1;
        if (tk + 4 < NTK) {
            const size_t o = (size_t)(tk + 4) * 512;
            na0 = *(const short8*)(a0p + o);
            na1 = *(const short8*)(a1p + o);
            nb0 = *(const short8*)(b0p + o);
            nb1 = *(const short8*)(b1p + o);
        }
        acc00 = __builtin_amdgcn_mfma_f32_32x32x16_bf16(ra0[s], rb0[s], acc00, 0, 0, 0);
        acc01 = __builtin_amdgcn_mfma_f32_32x32x16_bf16(ra0[s], rb1[s], acc01, 0, 0, 0);
        acc10 = __builtin_amdgcn_mfma_f32_32x32x16_bf16(ra1[s], rb0[s], acc10, 0, 0, 0);
        acc11 = __builtin_amdgcn_mfma_f32_32x32x16_bf16(ra1[s], rb1[s], acc11, 0, 0, 0);
        if (tk + 4 < NTK) {
            ra0[s] = na0; ra1[s] = na1; rb0[s] = nb0; rb1[s] = nb1;
        }
    }

    // ---- epilogue ----
    // (a) max (layout-invariant)
    float m = -3.4e38f;
#pragma unroll
    for (int i = 0; i < 16; ++i) {
        m = fmaxf(m, acc00[i]); m = fmaxf(m, acc01[i]);
        m = fmaxf(m, acc10[i]); m = fmaxf(m, acc11[i]);
    }
#pragma unroll
    for (int off = 32; off; off >>= 1)
        m = fmaxf(m, __shfl_down(m, off));
    __shared__ float wred[4];
    if (lane == 0) wred[wave] = m;

    // (b) column sums over m (decom_2): fixed n = lane&31 per lane
    float cs0 = 0.f, cs1 = 0.f;
#pragma unroll
    for (int r = 0; r < 16; ++r) {
        cs0 += acc00[r] + acc10[r];
        cs1 += acc01[r] + acc11[r];
    }
    cs0 += __shfl_xor(cs0, 32);
    cs1 += __shfl_xor(cs1, 32);
    if (lane < 32) {
        atomicAdd(&sal2[tnB * 32 + lane], cs0);
        atomicAdd(&sal2[(tnB + 1) * 32 + lane], cs1);
    }

    // (c) row sums over n (decom_1): butterfly over lane bits 0..4 (n-cols)
    float rs0[16], rs1[16];
#pragma unroll
    for (int r = 0; r < 16; ++r) {
        rs0[r] = acc00[r] + acc01[r];
        rs1[r] = acc10[r] + acc11[r];
    }
#pragma unroll
    for (int off = 1; off < 32; off <<= 1)
#pragma unroll
        for (int r = 0; r < 16; ++r) {
            rs0[r] += __shfl_xor(rs0[r], off);
            rs1[r] += __shfl_xor(rs1[r], off);
        }
    if ((lane & 31) == 0) {
        const int h = lane >> 5;
#pragma unroll
        for (int r = 0; r < 16; ++r) {
            const int row = (r & 3) + 8 * (r >> 2) + 4 * h;
            atomicAdd(&sal1[tmA * 32 + row], rs0[r]);
            atomicAdd(&sal1[(tmA + 1) * 32 + row], rs1[r]);
        }
    }

    __syncthreads();
    if (tid == 0)
        blockmax[blockIdx.y * gridDim.x + blockIdx.x] =
            fmaxf(fmaxf(wred[0], wred[1]), fmaxf(wred[2], wred[3]));
}

// ---------------------------------------------------------------------------
// Kernel 3: fused max-reduce + normalize + half-pixel bilinear 64->224.
__global__ __launch_bounds__(256) void resize_kernel(
    const float* __restrict__ sal, const float* __restrict__ bmax,
    float* __restrict__ out) {
    __shared__ float w[4];
    __shared__ float rM;
    const int tid = threadIdx.x;
    float m = -3.4e38f;
    for (int i = tid; i < 1024; i += 256) m = fmaxf(m, bmax[i]);
#pragma unroll
    for (int off = 32; off; off >>= 1) m = fmaxf(m, __shfl_down(m, off));
    if ((tid & 63) == 0) w[tid >> 6] = m;
    __syncthreads();
    if (tid == 0)
        rM = 1.0f / fmaxf(fmaxf(w[0], w[1]), fmaxf(w[2], w[3]));
    __syncthreads();

    const int idx = blockIdx.x * 256 + tid;
    if (idx >= 2 * IMG * IMG) return;
    const int ch = idx / (IMG * IMG);
    const int rem = idx % (IMG * IMG);
    const int oy = rem / IMG, ox = rem % IMG;
    const float scale = 64.0f / (float)IMG;
    const float sy = ((float)oy + 0.5f) * scale - 0.5f;
    const float sx = ((float)ox + 0.5f) * scale - 0.5f;
    const float fy0 = floorf(sy), fx0 = floorf(sx);
    const float wy = sy - fy0, wx = sx - fx0;
    int y0 = (int)fy0, x0 = (int)fx0;
    int y1 = min(max(y0 + 1, 0), 63), x1 = min(max(x0 + 1, 0), 63);
    y0 = min(max(y0, 0), 63); x0 = min(max(x0, 0), 63);
    const float* p = sal + ch * HW;
    const float v00 = p[y0 * 64 + x0], v01 = p[y0 * 64 + x1];
    const float v10 = p[y1 * 64 + x0], v11 = p[y1 * 64 + x1];
    out[idx] = ((1.f - wy) * ((1.f - wx) * v00 + wx * v01) +
                wy * ((1.f - wx) * v10 + wx * v11)) * rM;
}

// ---------------------------------------------------------------------------
extern "C" void kernel_launch(void* const* d_in, const int* in_sizes, int n_in,
                              void* d_out, int out_size, void* d_ws, size_t ws_size,
                              hipStream_t stream) {
    const float* feat = (const float*)d_in[0];   // [2,64,64,2048] fp32
    float* out = (float*)d_out;                  // [2,224,224] fp32

    // workspace layout
    char* ws = (char*)d_ws;
    short* Ap = (short*)ws;                                         // 16 MB packed
    short* Bp = (short*)(ws + (size_t)16 * 1024 * 1024);            // 16 MB packed
    float* sal  = (float*)(ws + (size_t)32 * 1024 * 1024);          // 8192 (sal1|sal2)
    float* bmax = sal + 2 * HW;                                     // 1024

    // zero the saliency accumulators (ws is poisoned 0xAA each launch)
    hipMemsetAsync(sal, 0, 2 * HW * sizeof(float), stream);

    convert_pack<<<dim3(4, 128, 2), 256, 0, stream>>>(feat, Ap, Bp);
    gemm_fused_kernel<<<dim3(32, 32), 256, 0, stream>>>(Ap, Bp, sal, sal + HW, bmax);
    const int nout = 2 * IMG * IMG;
    resize_kernel<<<(nout + 255) / 256, 256, 0, stream>>>(sal, bmax, out);
}